// Round 1
// baseline (164.132 us; speedup 1.0000x reference)
//
#include <hip/hip_runtime.h>
#include <hip/hip_bf16.h>
#include <cstdint>
#include <cstddef>

// Problem constants
constexpr int NB = 32;     // batch
constexpr int NH = 16;     // heads
constexpr int NS = 8192;   // seq len (cache)
constexpr int NK = 2048;   // top-k
constexpr int NL = 512;    // kv lora rank (latent)
constexpr int NDR = 64;    // rope dim
constexpr int NDV = 128;   // v head dim
constexpr int NDM = 2048;  // model dim
constexpr int NDN = 128;   // nope dim
constexpr float SCALE = 0.07216878364870322f; // 1/sqrt(192)

constexpr int NSPLIT = 16;     // K splits for flash partials
constexpr int KC = NK / NSPLIT; // 128 k per block
constexpr int NS2 = 32;        // n-splits for final GEMM

// ---------------- Kernel 1: q_latent[b,h,l] = sum_d q_nope[b,h,d] * W_UK[l,h,d]
__global__ void k_qlatent(const float* __restrict__ qn,
                          const float* __restrict__ wuk,
                          float* __restrict__ ql) {
  int bh = blockIdx.x;           // b*NH + h
  int h = bh & (NH - 1);
  __shared__ float q[NDN];
  int t = threadIdx.x;
  if (t < NDN) q[t] = qn[(size_t)bh * NDN + t];
  __syncthreads();
  for (int l = t; l < NL; l += 256) {
    const float4* wr = (const float4*)&wuk[((size_t)l * NH + h) * NDN];
    float acc = 0.f;
    #pragma unroll
    for (int j = 0; j < NDN / 4; ++j) {
      float4 wv = wr[j];
      float4 qv = *(const float4*)&q[j * 4];
      acc += wv.x * qv.x + wv.y * qv.y + wv.z * qv.z + wv.w * qv.w;
    }
    ql[(size_t)bh * NL + l] = acc;
  }
}

// ---------------- Kernel 2: per (b, split): scores -> softmax partial -> PV partial
// LDS: qle[16][576] fp32 (q_latent ++ q_pe), kv tile 64 rows x 16 float4 (pad 17),
//      p[16][132], idx[128]
__global__ __launch_bounds__(256, 2)
void k_attn_part(const float* __restrict__ qpe,
                 const float* __restrict__ kvc,
                 const float* __restrict__ kpe,
                 const int*   __restrict__ topk,
                 const float* __restrict__ ql_ws,
                 float* __restrict__ pm,
                 float* __restrict__ psum,
                 float* __restrict__ po) {
  const int sp = blockIdx.x;   // 0..NSPLIT-1
  const int b  = blockIdx.y;   // 0..NB-1
  const int t  = threadIdx.x;
  const int w  = t >> 6;       // wave 0..3
  const int lane = t & 63;

  __shared__ __align__(16) float qle[NH * 576];      // 36864 B
  __shared__ float4 kvt[64 * 17];                    // 17408 B
  __shared__ float plds[NH * 132];                   // 8448 B
  __shared__ int idxl[KC];

  // load q_latent and q_pe into qle
  for (int i = t; i < NH * NL; i += 256)
    qle[(i >> 9) * 576 + (i & 511)] = ql_ws[(size_t)b * NH * NL + i];
  for (int i = t; i < NH * NDR; i += 256)
    qle[(i >> 6) * 576 + 512 + (i & 63)] = qpe[(size_t)b * NH * NDR + i];
  if (t < KC) idxl[t] = topk[(size_t)b * NK + sp * KC + t];
  __syncthreads();

  const int r  = t >> 2;   // staging row 0..63
  const int j0 = t & 3;    // staging col group

  // -------- scores --------
  float acc[2][4];
  #pragma unroll
  for (int a = 0; a < 2; ++a)
    #pragma unroll
    for (int j = 0; j < 4; ++j) acc[a][j] = 0.f;

  const int h0 = w * 4;
  for (int ksub = 0; ksub < 2; ++ksub) {
    for (int c = 0; c < 9; ++c) {
      __syncthreads();  // protect tile from previous readers
      {
        int idx = idxl[ksub * 64 + r];
        int id = idx < 0 ? 0 : (idx >= NS ? NS - 1 : idx);
        const float4* s4 = (c < 8)
          ? (const float4*)&kvc[((size_t)b * NS + id) * NL + c * 64]
          : (const float4*)&kpe[((size_t)b * NS + id) * NDR];
        float4* dst = &kvt[r * 17];
        #pragma unroll
        for (int i = 0; i < 4; ++i) {
          int j = j0 + 4 * i;
          dst[j] = s4[j];
        }
      }
      __syncthreads();
      #pragma unroll 4
      for (int j4 = 0; j4 < 16; ++j4) {
        float4 kv4 = kvt[lane * 17 + j4];
        #pragma unroll
        for (int jh = 0; jh < 4; ++jh) {
          float4 q4 = *(const float4*)&qle[(h0 + jh) * 576 + c * 64 + j4 * 4];
          acc[ksub][jh] += kv4.x * q4.x + kv4.y * q4.y + kv4.z * q4.z + kv4.w * q4.w;
        }
      }
    }
  }

  // -------- per-wave softmax partial (wave w owns heads h0..h0+3 fully) --------
  bool v0 = idxl[lane] >= 0;
  bool v1 = idxl[64 + lane] >= 0;
  #pragma unroll
  for (int jh = 0; jh < 4; ++jh) {
    float s0 = v0 ? acc[0][jh] * SCALE : -INFINITY;
    float s1 = v1 ? acc[1][jh] * SCALE : -INFINITY;
    float m = fmaxf(s0, s1);
    #pragma unroll
    for (int off = 32; off; off >>= 1) m = fmaxf(m, __shfl_xor(m, off));
    if (m < -1e37f) m = -1e37f;  // all-invalid guard
    float p0 = __expf(s0 - m);
    float p1 = __expf(s1 - m);
    float s = p0 + p1;
    #pragma unroll
    for (int off = 32; off; off >>= 1) s += __shfl_xor(s, off);
    plds[(h0 + jh) * 132 + lane] = p0;
    plds[(h0 + jh) * 132 + 64 + lane] = p1;
    if (lane == 0) {
      pm[((size_t)b * NSPLIT + sp) * NH + h0 + jh] = m;
      psum[((size_t)b * NSPLIT + sp) * NH + h0 + jh] = s;
    }
  }

  // -------- PV: o_part[h][l] = sum_k p[h][k] * kv[k][l] --------
  const int h   = t >> 4;   // 0..15
  const int m16 = t & 15;   // float4 col within 64-float chunk
  float4 oacc[8];
  #pragma unroll
  for (int c = 0; c < 8; ++c) oacc[c] = make_float4(0.f, 0.f, 0.f, 0.f);

  for (int ksub = 0; ksub < 2; ++ksub) {
    for (int c = 0; c < 8; ++c) {
      __syncthreads();
      {
        int idx = idxl[ksub * 64 + r];
        int id = idx < 0 ? 0 : (idx >= NS ? NS - 1 : idx);
        const float4* s4 = (const float4*)&kvc[((size_t)b * NS + id) * NL + c * 64];
        float4* dst = &kvt[r * 17];
        #pragma unroll
        for (int i = 0; i < 4; ++i) {
          int j = j0 + 4 * i;
          dst[j] = s4[j];
        }
      }
      __syncthreads();
      #pragma unroll 4
      for (int k = 0; k < 64; ++k) {
        float pk = plds[h * 132 + ksub * 64 + k];
        float4 kv4 = kvt[k * 17 + m16];
        oacc[c].x += pk * kv4.x;
        oacc[c].y += pk * kv4.y;
        oacc[c].z += pk * kv4.z;
        oacc[c].w += pk * kv4.w;
      }
    }
  }

  float* dst = po + (((size_t)b * NSPLIT + sp) * NH + h) * NL;
  #pragma unroll
  for (int c = 0; c < 8; ++c)
    *(float4*)&dst[c * 64 + m16 * 4] = oacc[c];
}

// ---------------- Kernel 3: combine splits, project with W_UV -> ov[b, h*DV + v]
__global__ void k_combine(const float* __restrict__ pm,
                          const float* __restrict__ psum,
                          const float* __restrict__ po,
                          const float* __restrict__ wuv,
                          float* __restrict__ ov) {
  int bh = blockIdx.x;
  int b = bh >> 4, h = bh & 15;
  __shared__ float coef[NSPLIT];
  __shared__ float ol[NL];
  int t = threadIdx.x;
  if (t < NSPLIT) {
    float m = pm[((size_t)b * NSPLIT + t) * NH + h];
    float M = m;
    #pragma unroll
    for (int off = 8; off; off >>= 1) M = fmaxf(M, __shfl_xor(M, off, 16));
    float term = psum[((size_t)b * NSPLIT + t) * NH + h] * __expf(m - M);
    float S = term;
    #pragma unroll
    for (int off = 8; off; off >>= 1) S += __shfl_xor(S, off, 16);
    coef[t] = __expf(m - M) / S;
  }
  __syncthreads();
  for (int l = t; l < NL; l += 256) {
    float a = 0.f;
    for (int i = 0; i < NSPLIT; ++i)
      a += coef[i] * po[(((size_t)b * NSPLIT + i) * NH + h) * NL + l];
    ol[l] = a;
  }
  __syncthreads();
  if (t < NDV) {
    float a = 0.f;
    for (int l = 0; l < NL; ++l)
      a += ol[l] * wuv[((size_t)l * NH + h) * NDV + t];
    ov[(size_t)bh * NDV + t] = a;
  }
}

// ---------------- Kernel 4: GEMM partials: gp[ns][b][m] = sum_{n in chunk} ov[b][n]*W_O[n][m]
__global__ void k_gemm_part(const float* __restrict__ ov,
                            const float* __restrict__ wo,
                            float* __restrict__ gp) {
  int mc = blockIdx.x;  // 0..7
  int ns = blockIdx.y;  // 0..NS2-1
  __shared__ float oc[NB * 64];
  int t = threadIdx.x;
  for (int i = t; i < NB * 64; i += 256) {
    int b = i >> 6, n = i & 63;
    oc[i] = ov[(size_t)b * NDM + ns * 64 + n];
  }
  __syncthreads();
  float acc[NB];
  #pragma unroll
  for (int b = 0; b < NB; ++b) acc[b] = 0.f;
  int m = mc * 256 + t;
  for (int n = 0; n < 64; ++n) {
    float wv = wo[(size_t)(ns * 64 + n) * NDM + m];
    #pragma unroll
    for (int b = 0; b < NB; ++b) acc[b] += oc[b * 64 + n] * wv;
  }
  #pragma unroll
  for (int b = 0; b < NB; ++b)
    gp[((size_t)ns * NB + b) * NDM + m] = acc[b];
}

// ---------------- Kernel 5: reduce GEMM partials
__global__ void k_reduce(const float* __restrict__ gp, float* __restrict__ out) {
  int g = blockIdx.x * 256 + threadIdx.x;  // 0..NB*NDM-1
  float a = 0.f;
  for (int i = 0; i < NS2; ++i)
    a += gp[(size_t)i * (NB * NDM) + g];
  out[g] = a;
}

extern "C" void kernel_launch(void* const* d_in, const int* in_sizes, int n_in,
                              void* d_out, int out_size, void* d_ws, size_t ws_size,
                              hipStream_t stream) {
  const float* q_nope = (const float*)d_in[0];
  const float* q_pe   = (const float*)d_in[1];
  const float* kv_c   = (const float*)d_in[2];
  const float* k_pe   = (const float*)d_in[3];
  const float* W_UK   = (const float*)d_in[4];
  const float* W_UV   = (const float*)d_in[5];
  const float* W_O    = (const float*)d_in[6];
  const int*   topk   = (const int*)d_in[7];
  float* out = (float*)d_out;

  float* ws = (float*)d_ws;
  float* ql   = ws;                          // B*H*L      = 262144
  float* pm   = ql + (size_t)NB * NH * NL;   // B*NSPLIT*H = 8192
  float* psum = pm + (size_t)NB * NSPLIT * NH;
  float* po   = psum + (size_t)NB * NSPLIT * NH;       // B*NSPLIT*H*L = 4194304
  float* ov   = po + (size_t)NB * NSPLIT * NH * NL;    // B*H*DV = 65536
  float* gp   = ov + (size_t)NB * NH * NDV;            // NS2*B*DM = 2097152

  k_qlatent<<<NB * NH, 256, 0, stream>>>(q_nope, W_UK, ql);
  k_attn_part<<<dim3(NSPLIT, NB), 256, 0, stream>>>(q_pe, kv_c, k_pe, topk, ql,
                                                    pm, psum, po);
  k_combine<<<NB * NH, 256, 0, stream>>>(pm, psum, po, W_UV, ov);
  k_gemm_part<<<dim3(8, NS2), 256, 0, stream>>>(ov, W_O, gp);
  k_reduce<<<(NB * NDM) / 256, 256, 0, stream>>>(gp, out);
}

// Round 3
// 124.188 us; speedup vs baseline: 1.3216x; 1.3216x over previous
//
#include <hip/hip_runtime.h>
#include <hip/hip_bf16.h>
#include <cstdint>
#include <cstddef>

// Problem constants
constexpr int NB = 32;     // batch
constexpr int NH = 16;     // heads
constexpr int NS = 8192;   // seq len
constexpr int NK = 2048;   // top-k
constexpr int NL = 512;    // latent dim
constexpr int NDR = 64;    // rope dim
constexpr int NDV = 128;   // v head dim
constexpr int NDM = 2048;  // model dim
constexpr int NDN = 128;   // nope dim
constexpr float SCALE = 0.07216878364870322f; // 1/sqrt(192)

constexpr int NSPLIT = 32;      // k-splits
constexpr int KC = NK / NSPLIT; // 64 k per block
constexpr int ND = NL + NDR;    // 576 staged dims
constexpr int NSUB_D = ND / 16; // 36 subtiles per 4-row group
constexpr int NS2 = 32;         // n-splits for final GEMM

typedef __attribute__((ext_vector_type(8))) short sh8;
typedef __attribute__((ext_vector_type(4))) float f32x4;

__device__ __forceinline__ short bf16c(float f) {
  union { float f; uint32_t u; } v; v.f = f;
  uint32_t r = v.u + 0x7fffu + ((v.u >> 16) & 1u);
  return (short)(r >> 16);
}

__device__ __forceinline__ sh8 pack_bf8(float4 a, float4 b) {
  sh8 f;
  f[0] = bf16c(a.x); f[1] = bf16c(a.y); f[2] = bf16c(a.z); f[3] = bf16c(a.w);
  f[4] = bf16c(b.x); f[5] = bf16c(b.y); f[6] = bf16c(b.z); f[7] = bf16c(b.w);
  return f;
}

// ---------------- Kernel 1: q_latent[b,h,l] = sum_d q_nope[b,h,d] * W_UK[l,h,d]
__global__ void k_qlatent(const float* __restrict__ qn,
                          const float* __restrict__ wuk,
                          float* __restrict__ ql) {
  int bh = blockIdx.x;
  int h = bh & (NH - 1);
  __shared__ float q[NDN];
  int t = threadIdx.x;
  if (t < NDN) q[t] = qn[(size_t)bh * NDN + t];
  __syncthreads();
  for (int l = t; l < NL; l += 256) {
    const float4* wr = (const float4*)&wuk[((size_t)l * NH + h) * NDN];
    float acc = 0.f;
    #pragma unroll
    for (int j = 0; j < NDN / 4; ++j) {
      float4 wv = wr[j];
      float4 qv = *(const float4*)&q[j * 4];
      acc += wv.x * qv.x + wv.y * qv.y + wv.z * qv.z + wv.w * qv.w;
    }
    ql[(size_t)bh * NL + l] = acc;
  }
}

// ---------------- Kernel 2: MFMA flash attention partial per (split, b)
__global__ __launch_bounds__(256, 2)
void k_attn(const float* __restrict__ qpe,
            const float* __restrict__ kvc,
            const float* __restrict__ kpe,
            const int*   __restrict__ topk,
            const float* __restrict__ ql_ws,
            float* __restrict__ pm,
            float* __restrict__ psum,
            float* __restrict__ po) {
  const int sp = blockIdx.x;     // 0..NSPLIT-1
  const int b  = blockIdx.y;     // 0..NB-1
  const int t  = threadIdx.x;
  const int w  = t >> 6;         // wave 0..3
  const int lane = t & 63;
  const int lg = lane >> 4;      // lane group 0..3
  const int ln = lane & 15;

  // kv tile, bf16, subtiled: elem (k,d) at ((k>>2)*36 + (d>>4))*64 + (k&3)*16 + (d&15)
  __shared__ __align__(16) short kvs[(KC / 4) * NSUB_D * 64];   // 73728 B
  __shared__ __align__(16) short plds[NH * 72];                 // P bf16, row stride 72
  __shared__ float mlds[4 * NH];
  __shared__ float slds[4 * NH];

  // ---- q fragments from global (fp32 -> bf16), A-frag: row h = ln, d = kk*32 + lg*8 + j
  sh8 qf[18];
  {
    const float* qlrow = ql_ws + ((size_t)b * NH + ln) * NL;
    const float* qprow = qpe + ((size_t)b * NH + ln) * NDR;
    #pragma unroll
    for (int kk = 0; kk < 18; ++kk) {
      int d0 = kk * 32 + lg * 8;
      const float* src = (kk < 16) ? (qlrow + d0) : (qprow + (d0 - NL));
      float4 a = *(const float4*)src;
      float4 bb = *(const float4*)(src + 4);
      qf[kk] = pack_bf8(a, bb);
    }
  }

  // ---- gather-stage kv tile (64 rows x 576) as bf16 into subtiled LDS
  {
    const int r = t >> 2, c8 = t & 3;
    int idx = topk[(size_t)b * NK + sp * KC + r];
    int id = idx < 0 ? 0 : (idx >= NS ? NS - 1 : idx);
    const float* rowc = kvc + ((size_t)b * NS + id) * NL;
    const float* rowp = kpe + ((size_t)b * NS + id) * NDR;
    #pragma unroll
    for (int i = 0; i < 18; ++i) {
      int d0 = c8 * 8 + i * 32;
      const float* src = (d0 < NL) ? (rowc + d0) : (rowp + (d0 - NL));
      float4 a = *(const float4*)src;
      float4 bb = *(const float4*)(src + 4);
      int s = (r >> 2) * NSUB_D + (d0 >> 4);
      *(sh8*)&kvs[s * 64 + (r & 3) * 16 + (d0 & 15)] = pack_bf8(a, bb);
    }
  }
  __syncthreads();

  // ---- QK^T: wave w owns k-tile [w*16, w*16+16)
  f32x4 accs = {0.f, 0.f, 0.f, 0.f};
  {
    int k = w * 16 + ln;
    int kbase = (k >> 2) * NSUB_D * 64 + (k & 3) * 16;
    #pragma unroll
    for (int kk = 0; kk < 18; ++kk) {
      int d0 = kk * 32 + lg * 8;
      sh8 bfr = *(const sh8*)&kvs[kbase + (d0 >> 4) * 64 + (d0 & 15)];
      accs = __builtin_amdgcn_mfma_f32_16x16x32_bf16(qf[kk], bfr, accs, 0, 0, 0);
    }
  }

  // ---- softmax over the 64 k of this split (cross-wave via LDS)
  const int kq = w * 16 + ln;
  bool valid = topk[(size_t)b * NK + sp * KC + kq] >= 0;
  float sv[4], mx[4];
  #pragma unroll
  for (int r = 0; r < 4; ++r) {
    sv[r] = valid ? accs[r] * SCALE : -INFINITY;
    mx[r] = sv[r];
  }
  #pragma unroll
  for (int off = 1; off < 16; off <<= 1)
    #pragma unroll
    for (int r = 0; r < 4; ++r) mx[r] = fmaxf(mx[r], __shfl_xor(mx[r], off));
  if (ln == 0) {
    #pragma unroll
    for (int r = 0; r < 4; ++r) mlds[w * NH + lg * 4 + r] = mx[r];
  }
  __syncthreads();

  float pr[4], sm[4];
  #pragma unroll
  for (int r = 0; r < 4; ++r) {
    int h = lg * 4 + r;
    float m = fmaxf(fmaxf(mlds[h], mlds[NH + h]),
                    fmaxf(mlds[2 * NH + h], mlds[3 * NH + h]));
    m = fmaxf(m, -1e30f);
    pr[r] = __expf(sv[r] - m);
    sm[r] = pr[r];
  }
  #pragma unroll
  for (int off = 1; off < 16; off <<= 1)
    #pragma unroll
    for (int r = 0; r < 4; ++r) sm[r] += __shfl_xor(sm[r], off);
  if (ln == 0) {
    #pragma unroll
    for (int r = 0; r < 4; ++r) slds[w * NH + lg * 4 + r] = sm[r];
  }
  // P -> bf16 -> LDS  (row h, col k)
  #pragma unroll
  for (int r = 0; r < 4; ++r)
    plds[(lg * 4 + r) * 72 + kq] = bf16c(pr[r]);
  __syncthreads();

  if (t < NH) {
    float m = fmaxf(fmaxf(mlds[t], mlds[NH + t]),
                    fmaxf(mlds[2 * NH + t], mlds[3 * NH + t]));
    m = fmaxf(m, -1e30f);
    float s = slds[t] + slds[NH + t] + slds[2 * NH + t] + slds[3 * NH + t];
    pm[((size_t)b * NSPLIT + sp) * NH + t] = m;
    psum[((size_t)b * NSPLIT + sp) * NH + t] = s;
  }

  // ---- PV: O[h][l] partial; wave w owns l-range [w*128, w*128+128)
  // B-frag gathered with plain ds_read_u16 (unambiguous semantics):
  //   bv[j] = KV[kb + j][l0 + ln]  from subtiled kvs
  f32x4 acco[8];
  #pragma unroll
  for (int nt = 0; nt < 8; ++nt) acco[nt] = {0.f, 0.f, 0.f, 0.f};

  #pragma unroll
  for (int ks = 0; ks < 2; ++ks) {
    sh8 pa = *(const sh8*)&plds[ln * 72 + ks * 32 + lg * 8];  // A-frag: P[h=ln][k]
    int kb = ks * 32 + lg * 8;                                // k base (mult of 8)
    #pragma unroll
    for (int nt = 0; nt < 8; ++nt) {
      int l0 = w * 128 + nt * 16;
      int s = (kb >> 2) * NSUB_D + (l0 >> 4);
      const short* base = &kvs[s * 64 + ln];
      sh8 bv;
      #pragma unroll
      for (int j = 0; j < 4; ++j) bv[j] = base[j * 16];
      #pragma unroll
      for (int j = 0; j < 4; ++j) bv[4 + j] = base[NSUB_D * 64 + j * 16];
      acco[nt] = __builtin_amdgcn_mfma_f32_16x16x32_bf16(pa, bv, acco[nt], 0, 0, 0);
    }
  }

  // ---- write po partial [b][sp][h][l]
  float* dst = po + (((size_t)b * NSPLIT + sp) * NH) * NL;
  #pragma unroll
  for (int nt = 0; nt < 8; ++nt) {
    int l = w * 128 + nt * 16 + ln;
    #pragma unroll
    for (int r = 0; r < 4; ++r) {
      int h = lg * 4 + r;
      dst[(size_t)h * NL + l] = acco[nt][r];
    }
  }
}

// ---------------- Kernel 3: combine splits, project with W_UV -> ov[b, h*DV + v]
__global__ void k_combine(const float* __restrict__ pm,
                          const float* __restrict__ psum,
                          const float* __restrict__ po,
                          const float* __restrict__ wuv,
                          float* __restrict__ ov) {
  int bh = blockIdx.x;
  int b = bh >> 4, h = bh & 15;
  __shared__ float coef[NSPLIT];
  __shared__ float ol[NL];
  int t = threadIdx.x;
  if (t < NSPLIT) {
    float m = pm[((size_t)b * NSPLIT + t) * NH + h];
    float M = m;
    #pragma unroll
    for (int off = 16; off; off >>= 1) M = fmaxf(M, __shfl_xor(M, off, 32));
    float term = psum[((size_t)b * NSPLIT + t) * NH + h] * __expf(m - M);
    float S = term;
    #pragma unroll
    for (int off = 16; off; off >>= 1) S += __shfl_xor(S, off, 32);
    coef[t] = __expf(m - M) / fmaxf(S, 1e-30f);
  }
  __syncthreads();
  for (int l = t; l < NL; l += 256) {
    float a = 0.f;
    #pragma unroll
    for (int i = 0; i < NSPLIT; ++i)
      a += coef[i] * po[(((size_t)b * NSPLIT + i) * NH + h) * NL + l];
    ol[l] = a;
  }
  __syncthreads();
  if (t < NDV) {
    float a = 0.f;
    for (int l = 0; l < NL; ++l)
      a += ol[l] * wuv[((size_t)l * NH + h) * NDV + t];
    ov[(size_t)bh * NDV + t] = a;
  }
}

// ---------------- Kernel 4: GEMM partials over n-chunks of 64
__global__ void k_gemm_part(const float* __restrict__ ov,
                            const float* __restrict__ wo,
                            float* __restrict__ gp) {
  int mc = blockIdx.x;  // 0..7
  int ns = blockIdx.y;  // 0..NS2-1
  __shared__ float oc[NB * 64];
  int t = threadIdx.x;
  for (int i = t; i < NB * 64; i += 256) {
    int b = i >> 6, n = i & 63;
    oc[i] = ov[(size_t)b * NDM + ns * 64 + n];
  }
  __syncthreads();
  float acc[NB];
  #pragma unroll
  for (int b = 0; b < NB; ++b) acc[b] = 0.f;
  int m = mc * 256 + t;
  for (int n = 0; n < 64; ++n) {
    float wv = wo[(size_t)(ns * 64 + n) * NDM + m];
    #pragma unroll
    for (int b = 0; b < NB; ++b) acc[b] += oc[b * 64 + n] * wv;
  }
  #pragma unroll
  for (int b = 0; b < NB; ++b)
    gp[((size_t)ns * NB + b) * NDM + m] = acc[b];
}

// ---------------- Kernel 5: reduce GEMM partials
__global__ void k_reduce(const float* __restrict__ gp, float* __restrict__ out) {
  int g = blockIdx.x * 256 + threadIdx.x;
  float a = 0.f;
  for (int i = 0; i < NS2; ++i)
    a += gp[(size_t)i * (NB * NDM) + g];
  out[g] = a;
}

extern "C" void kernel_launch(void* const* d_in, const int* in_sizes, int n_in,
                              void* d_out, int out_size, void* d_ws, size_t ws_size,
                              hipStream_t stream) {
  const float* q_nope = (const float*)d_in[0];
  const float* q_pe   = (const float*)d_in[1];
  const float* kv_c   = (const float*)d_in[2];
  const float* k_pe   = (const float*)d_in[3];
  const float* W_UK   = (const float*)d_in[4];
  const float* W_UV   = (const float*)d_in[5];
  const float* W_O    = (const float*)d_in[6];
  const int*   topk   = (const int*)d_in[7];
  float* out = (float*)d_out;

  float* ws = (float*)d_ws;
  float* ql   = ws;                                    // 262144
  float* pm   = ql + (size_t)NB * NH * NL;             // 16384
  float* psum = pm + (size_t)NB * NSPLIT * NH;         // 16384
  float* po   = psum + (size_t)NB * NSPLIT * NH;       // 8388608 (fp32)
  float* ov   = po + (size_t)NB * NSPLIT * NH * NL;    // 65536
  float* gp   = ov + (size_t)NB * NH * NDV;            // 2097152

  k_qlatent<<<NB * NH, 256, 0, stream>>>(q_nope, W_UK, ql);
  k_attn<<<dim3(NSPLIT, NB), 256, 0, stream>>>(q_pe, kv_c, k_pe, topk, ql,
                                               pm, psum, po);
  k_combine<<<NB * NH, 256, 0, stream>>>(pm, psum, po, W_UV, ov);
  k_gemm_part<<<dim3(8, NS2), 256, 0, stream>>>(ov, W_O, gp);
  k_reduce<<<(NB * NDM) / 256, 256, 0, stream>>>(gp, out);
}

// Round 4
// 123.519 us; speedup vs baseline: 1.3288x; 1.0054x over previous
//
#include <hip/hip_runtime.h>
#include <hip/hip_bf16.h>
#include <cstdint>
#include <cstddef>

// Problem constants
constexpr int NB = 32;     // batch
constexpr int NH = 16;     // heads
constexpr int NS = 8192;   // seq len
constexpr int NK = 2048;   // top-k
constexpr int NL = 512;    // latent dim
constexpr int NDR = 64;    // rope dim
constexpr int NDV = 128;   // v head dim
constexpr int NDM = 2048;  // model dim
constexpr int NDN = 128;   // nope dim
constexpr float SCALE = 0.07216878364870322f; // 1/sqrt(192)

constexpr int NSPLIT = 32;      // k-splits
constexpr int KC = NK / NSPLIT; // 64 k per block
constexpr int ND = NL + NDR;    // 576 staged dims
constexpr int NSUB_D = ND / 16; // 36 subtiles per 4-row group
constexpr int NS2 = 32;         // n-splits for final GEMM

typedef __attribute__((ext_vector_type(8))) short sh8;
typedef __attribute__((ext_vector_type(4))) float f32x4;

__device__ __forceinline__ short bf16c(float f) {
  union { float f; uint32_t u; } v; v.f = f;
  uint32_t r = v.u + 0x7fffu + ((v.u >> 16) & 1u);
  return (short)(r >> 16);
}

__device__ __forceinline__ float bf2f(short s) {
  union { uint32_t u; float f; } v; v.u = ((uint32_t)(uint16_t)s) << 16;
  return v.f;
}

__device__ __forceinline__ sh8 pack_bf8(float4 a, float4 b) {
  sh8 f;
  f[0] = bf16c(a.x); f[1] = bf16c(a.y); f[2] = bf16c(a.z); f[3] = bf16c(a.w);
  f[4] = bf16c(b.x); f[5] = bf16c(b.y); f[6] = bf16c(b.z); f[7] = bf16c(b.w);
  return f;
}

// ---------------- Kernel 1: qle[b,h,0:512] = bf16(q_nope . W_UK), qle[b,h,512:576] = bf16(q_pe)
__global__ void k_qprep(const float* __restrict__ qn,
                        const float* __restrict__ qpe,
                        const float* __restrict__ wuk,
                        short* __restrict__ qle) {
  int bh = blockIdx.x;
  int h = bh & (NH - 1);
  __shared__ float q[NDN];
  int t = threadIdx.x;
  if (t < NDN) q[t] = qn[(size_t)bh * NDN + t];
  __syncthreads();
  for (int l = t; l < NL; l += 256) {
    const float4* wr = (const float4*)&wuk[((size_t)l * NH + h) * NDN];
    float acc = 0.f;
    #pragma unroll
    for (int j = 0; j < NDN / 4; ++j) {
      float4 wv = wr[j];
      float4 qv = *(const float4*)&q[j * 4];
      acc += wv.x * qv.x + wv.y * qv.y + wv.z * qv.z + wv.w * qv.w;
    }
    qle[(size_t)bh * ND + l] = bf16c(acc);
  }
  if (t < NDR) qle[(size_t)bh * ND + NL + t] = bf16c(qpe[(size_t)bh * NDR + t]);
}

// ---------------- Kernel 2: MFMA flash attention partial per (split, b)
__global__ __launch_bounds__(256, 2)
void k_attn(const float* __restrict__ kvc,
            const float* __restrict__ kpe,
            const int*   __restrict__ topk,
            const short* __restrict__ qle,
            float* __restrict__ pm,
            float* __restrict__ psum,
            unsigned short* __restrict__ po) {
  const int sp = blockIdx.x;     // 0..NSPLIT-1
  const int b  = blockIdx.y;     // 0..NB-1
  const int t  = threadIdx.x;
  const int w  = t >> 6;         // wave 0..3
  const int lane = t & 63;
  const int lg = lane >> 4;      // lane group 0..3
  const int ln = lane & 15;

  // kv tile, bf16, subtiled: elem (k,d) at ((k>>2)*36 + (d>>4))*64 + (k&3)*16 + (d&15)
  __shared__ __align__(16) short kvs[(KC / 4) * NSUB_D * 64];   // 73728 B
  __shared__ __align__(16) short plds[NH * 72];                 // P bf16, row stride 72
  __shared__ float mlds[4 * NH];
  __shared__ float slds[4 * NH];

  // ---- gather-stage kv tile (64 rows x 576) as bf16 into subtiled LDS
  // chunked 3x6 to bound register pressure (12 float4 in flight per chunk)
  {
    const int r = t >> 2, c8 = t & 3;
    int idx = topk[(size_t)b * NK + sp * KC + r];
    int id = idx < 0 ? 0 : (idx >= NS ? NS - 1 : idx);
    const float* rowc = kvc + ((size_t)b * NS + id) * NL;
    const float* rowp = kpe + ((size_t)b * NS + id) * NDR;
    #pragma unroll
    for (int g = 0; g < 3; ++g) {
      float4 va[6], vb[6];
      #pragma unroll
      for (int i = 0; i < 6; ++i) {
        int d0 = c8 * 8 + (g * 6 + i) * 32;
        const float* src = (d0 < NL) ? (rowc + d0) : (rowp + (d0 - NL));
        va[i] = *(const float4*)src;
        vb[i] = *(const float4*)(src + 4);
      }
      #pragma unroll
      for (int i = 0; i < 6; ++i) {
        int d0 = c8 * 8 + (g * 6 + i) * 32;
        int s = (r >> 2) * NSUB_D + (d0 >> 4);
        *(sh8*)&kvs[s * 64 + (r & 3) * 16 + (d0 & 15)] = pack_bf8(va[i], vb[i]);
      }
    }
  }
  __syncthreads();

  // ---- QK^T: wave w owns k-tile [w*16, w*16+16); A-frags streamed from L2-hot qle
  f32x4 accs = {0.f, 0.f, 0.f, 0.f};
  {
    const short* qrow = qle + ((size_t)b * NH + ln) * ND;
    int k = w * 16 + ln;
    int kbase = (k >> 2) * NSUB_D * 64 + (k & 3) * 16;
    #pragma unroll
    for (int kk = 0; kk < 18; ++kk) {
      int d0 = kk * 32 + lg * 8;
      sh8 qv = *(const sh8*)&qrow[d0];
      sh8 bfr = *(const sh8*)&kvs[kbase + (d0 >> 4) * 64 + (d0 & 15)];
      accs = __builtin_amdgcn_mfma_f32_16x16x32_bf16(qv, bfr, accs, 0, 0, 0);
    }
  }

  // ---- softmax over the 64 k of this split (cross-wave via LDS)
  const int kq = w * 16 + ln;
  bool valid = topk[(size_t)b * NK + sp * KC + kq] >= 0;
  float sv[4], mx[4];
  #pragma unroll
  for (int r = 0; r < 4; ++r) {
    sv[r] = valid ? accs[r] * SCALE : -INFINITY;
    mx[r] = sv[r];
  }
  #pragma unroll
  for (int off = 1; off < 16; off <<= 1)
    #pragma unroll
    for (int r = 0; r < 4; ++r) mx[r] = fmaxf(mx[r], __shfl_xor(mx[r], off));
  if (ln == 0) {
    #pragma unroll
    for (int r = 0; r < 4; ++r) mlds[w * NH + lg * 4 + r] = mx[r];
  }
  __syncthreads();

  float pr[4], sm[4];
  #pragma unroll
  for (int r = 0; r < 4; ++r) {
    int h = lg * 4 + r;
    float m = fmaxf(fmaxf(mlds[h], mlds[NH + h]),
                    fmaxf(mlds[2 * NH + h], mlds[3 * NH + h]));
    m = fmaxf(m, -1e30f);
    pr[r] = __expf(sv[r] - m);
    sm[r] = pr[r];
  }
  #pragma unroll
  for (int off = 1; off < 16; off <<= 1)
    #pragma unroll
    for (int r = 0; r < 4; ++r) sm[r] += __shfl_xor(sm[r], off);
  if (ln == 0) {
    #pragma unroll
    for (int r = 0; r < 4; ++r) slds[w * NH + lg * 4 + r] = sm[r];
  }
  // P -> bf16 -> LDS  (row h, col k)
  #pragma unroll
  for (int r = 0; r < 4; ++r)
    plds[(lg * 4 + r) * 72 + kq] = bf16c(pr[r]);
  __syncthreads();

  if (t < NH) {
    float m = fmaxf(fmaxf(mlds[t], mlds[NH + t]),
                    fmaxf(mlds[2 * NH + t], mlds[3 * NH + t]));
    m = fmaxf(m, -1e30f);
    float s = slds[t] + slds[NH + t] + slds[2 * NH + t] + slds[3 * NH + t];
    pm[((size_t)b * NSPLIT + sp) * NH + t] = m;
    psum[((size_t)b * NSPLIT + sp) * NH + t] = s;
  }

  // ---- PV: O[h][l] partial; wave w owns l-range [w*128, w*128+128)
  // B-frag gathered with plain ds_read_u16: bv[j] = KV[kb + j][l0 + ln]
  f32x4 acco[8];
  #pragma unroll
  for (int nt = 0; nt < 8; ++nt) acco[nt] = {0.f, 0.f, 0.f, 0.f};

  #pragma unroll
  for (int ks = 0; ks < 2; ++ks) {
    sh8 pa = *(const sh8*)&plds[ln * 72 + ks * 32 + lg * 8];  // A-frag: P[h=ln][k]
    int kb = ks * 32 + lg * 8;                                // k base (mult of 8)
    #pragma unroll
    for (int nt = 0; nt < 8; ++nt) {
      int l0 = w * 128 + nt * 16;
      int s = (kb >> 2) * NSUB_D + (l0 >> 4);
      const short* base = &kvs[s * 64 + ln];
      sh8 bv;
      #pragma unroll
      for (int j = 0; j < 4; ++j) bv[j] = base[j * 16];
      #pragma unroll
      for (int j = 0; j < 4; ++j) bv[4 + j] = base[NSUB_D * 64 + j * 16];
      acco[nt] = __builtin_amdgcn_mfma_f32_16x16x32_bf16(pa, bv, acco[nt], 0, 0, 0);
    }
  }

  // ---- write po partial bf16 [b][sp][h][l]
  unsigned short* dst = po + (((size_t)b * NSPLIT + sp) * NH) * NL;
  #pragma unroll
  for (int nt = 0; nt < 8; ++nt) {
    int l = w * 128 + nt * 16 + ln;
    #pragma unroll
    for (int r = 0; r < 4; ++r) {
      int h = lg * 4 + r;
      dst[(size_t)h * NL + l] = (unsigned short)bf16c(acco[nt][r]);
    }
  }
}

// ---------------- Kernel 3: combine splits, project with W_UV -> ov[b, h*DV + v]
__global__ void k_combine(const float* __restrict__ pm,
                          const float* __restrict__ psum,
                          const unsigned short* __restrict__ po,
                          const float* __restrict__ wuv,
                          float* __restrict__ ov) {
  int bh = blockIdx.x;
  int b = bh >> 4, h = bh & 15;
  __shared__ float coef[NSPLIT];
  __shared__ float ol[NL];
  __shared__ float red[2][NDV];
  int t = threadIdx.x;
  if (t < NSPLIT) {
    float m = pm[((size_t)b * NSPLIT + t) * NH + h];
    float M = m;
    #pragma unroll
    for (int off = 16; off; off >>= 1) M = fmaxf(M, __shfl_xor(M, off, 32));
    float term = psum[((size_t)b * NSPLIT + t) * NH + h] * __expf(m - M);
    float S = term;
    #pragma unroll
    for (int off = 16; off; off >>= 1) S += __shfl_xor(S, off, 32);
    coef[t] = __expf(m - M) / fmaxf(S, 1e-30f);
  }
  __syncthreads();
  for (int l = t; l < NL; l += 256) {
    float a = 0.f;
    #pragma unroll
    for (int i = 0; i < NSPLIT; ++i)
      a += coef[i] * bf2f((short)po[(((size_t)b * NSPLIT + i) * NH + h) * NL + l]);
    ol[l] = a;
  }
  __syncthreads();
  {
    int v = t & (NDV - 1);
    int half = t >> 7;
    float a = 0.f;
    #pragma unroll 4
    for (int l = half * 256; l < half * 256 + 256; ++l)
      a += ol[l] * wuv[((size_t)l * NH + h) * NDV + v];
    red[half][v] = a;
  }
  __syncthreads();
  if (t < NDV) ov[(size_t)bh * NDV + t] = red[0][t] + red[1][t];
}

// ---------------- Kernel 4: GEMM partials over n-chunks of 64
__global__ void k_gemm_part(const float* __restrict__ ov,
                            const float* __restrict__ wo,
                            float* __restrict__ gp) {
  int mc = blockIdx.x;  // 0..7
  int ns = blockIdx.y;  // 0..NS2-1
  __shared__ float oc[NB * 64];
  int t = threadIdx.x;
  for (int i = t; i < NB * 64; i += 256) {
    int b = i >> 6, n = i & 63;
    oc[i] = ov[(size_t)b * NDM + ns * 64 + n];
  }
  __syncthreads();
  float acc[NB];
  #pragma unroll
  for (int b = 0; b < NB; ++b) acc[b] = 0.f;
  int m = mc * 256 + t;
  for (int n = 0; n < 64; ++n) {
    float wv = wo[(size_t)(ns * 64 + n) * NDM + m];
    #pragma unroll
    for (int b = 0; b < NB; ++b) acc[b] += oc[b * 64 + n] * wv;
  }
  #pragma unroll
  for (int b = 0; b < NB; ++b)
    gp[((size_t)ns * NB + b) * NDM + m] = acc[b];
}

// ---------------- Kernel 5: reduce GEMM partials
__global__ void k_reduce(const float* __restrict__ gp, float* __restrict__ out) {
  int g = blockIdx.x * 256 + threadIdx.x;
  float a = 0.f;
  for (int i = 0; i < NS2; ++i)
    a += gp[(size_t)i * (NB * NDM) + g];
  out[g] = a;
}

extern "C" void kernel_launch(void* const* d_in, const int* in_sizes, int n_in,
                              void* d_out, int out_size, void* d_ws, size_t ws_size,
                              hipStream_t stream) {
  const float* q_nope = (const float*)d_in[0];
  const float* q_pe   = (const float*)d_in[1];
  const float* kv_c   = (const float*)d_in[2];
  const float* k_pe   = (const float*)d_in[3];
  const float* W_UK   = (const float*)d_in[4];
  const float* W_UV   = (const float*)d_in[5];
  const float* W_O    = (const float*)d_in[6];
  const int*   topk   = (const int*)d_in[7];
  float* out = (float*)d_out;

  float* ws = (float*)d_ws;
  short* qle = (short*)ws;                                     // NB*NH*576 bf16 = 147456 floats
  float* pm   = ws + 147456;                                   // 16384
  float* psum = pm + (size_t)NB * NSPLIT * NH;                 // 16384
  unsigned short* po = (unsigned short*)(psum + (size_t)NB * NSPLIT * NH); // 8.4M bf16 = 4194304 floats
  float* ov   = psum + (size_t)NB * NSPLIT * NH + 4194304;     // 65536
  float* gp   = ov + (size_t)NB * NH * NDV;                    // 2097152

  k_qprep<<<NB * NH, 256, 0, stream>>>(q_nope, q_pe, W_UK, qle);
  k_attn<<<dim3(NSPLIT, NB), 256, 0, stream>>>(kv_c, k_pe, topk, qle,
                                               pm, psum, po);
  k_combine<<<NB * NH, 256, 0, stream>>>(pm, psum, po, W_UV, ov);
  k_gemm_part<<<dim3(8, NS2), 256, 0, stream>>>(ov, W_O, gp);
  k_reduce<<<(NB * NDM) / 256, 256, 0, stream>>>(gp, out);
}